// Round 7
// baseline (191.483 us; speedup 1.0000x reference)
//
#include <hip/hip_runtime.h>
#include <hip/hip_bf16.h>

#define NPER 24
#define B_ 32
#define N_ 1024
#define F_ 128
#define H_ 64
#define E_ 16

typedef __attribute__((ext_vector_type(8))) short short8;
typedef __attribute__((ext_vector_type(4))) float f32x4;

static __device__ __forceinline__ unsigned short f2bf(float x) {
    union { float f; unsigned u; } v; v.f = x;
    unsigned r = v.u + 0x7fffu + ((v.u >> 16) & 1u);   // RNE
    return (unsigned short)(r >> 16);
}
static __device__ __forceinline__ float bf2f(unsigned short h) {
    union { unsigned u; float f; } v; v.u = ((unsigned)h) << 16; return v.f;
}
static __device__ __forceinline__ unsigned short f2bf_hw(float x) {
    __hip_bfloat16 h = __float2bfloat16(x);
    return *(unsigned short*)&h;
}

// ---------------------------------------------------------------------------
// P1: all prep in one launch.
//   blocks [0,256):     env encoder fused into src/tgt bf16 (24 periods)
//   blocks [256,1280):  adj -> bf16
//   blocks [1280,1408): W / res_W transpose -> bf16
// ---------------------------------------------------------------------------
__global__ __launch_bounds__(256) void prep_all(
    const float* __restrict__ src_emb, const float* __restrict__ tgt_emb,
    const float* __restrict__ env_features, const float* __restrict__ env_W,
    const float* __restrict__ env_b,
    const float* __restrict__ adj, const float* __restrict__ W,
    const float* __restrict__ rW,
    unsigned short* __restrict__ src_bf, unsigned short* __restrict__ tgt_bf,
    unsigned short* __restrict__ adj_bf, unsigned short* __restrict__ Wt,
    unsigned short* __restrict__ rWt)
{
    const int bid = blockIdx.x;
    if (bid < 256) {
        const int idx = bid * 256 + threadIdx.x;   // 0..65535
        const int n = idx >> 6, h = idx & 63;
        float e = env_b[h];
#pragma unroll
        for (int k = 0; k < E_; ++k)
            e = fmaf(env_features[n * E_ + k], env_W[k * H_ + h], e);
        e = fmaxf(e, 0.f);
#pragma unroll 4
        for (int p = 0; p < NPER; ++p) {
            const size_t off = (size_t)p * (N_ * H_) + idx;
            src_bf[off] = f2bf(src_emb[off] + e);
            tgt_bf[off] = f2bf(tgt_emb[off] + e);
        }
    } else if (bid < 1280) {
        const size_t i = ((size_t)(bid - 256) * 256 + threadIdx.x) * 4;
        float4 v = *(const float4*)(adj + i);
        ushort4 o;
        o.x = f2bf(v.x); o.y = f2bf(v.y); o.z = f2bf(v.z); o.w = f2bf(v.w);
        *(ushort4*)(adj_bf + i) = o;
    } else {
        const int idx = (bid - 1280) * 256 + threadIdx.x;   // 0..32767
        const int which = idx >> 14, j = idx & 16383;
        const int f = j >> 7, d = j & 127;
        if (which == 0) Wt[f * 128 + d]  = f2bf(W[d * 128 + f]);
        else            rWt[f * 128 + d] = f2bf(rW[d * 128 + f]);
    }
}

// ---------------------------------------------------------------------------
// K5: support^T (swapped GEMM) + residual, both bf16 out, MFMA. [verified]
// ---------------------------------------------------------------------------
__global__ __launch_bounds__(256) void gemm2_mfma(
    const float* __restrict__ x,               // [B*N][128] fp32
    const unsigned short* __restrict__ Wt,     // [128f][128d]
    const unsigned short* __restrict__ rWt,    // [128f][128d]
    const float* __restrict__ rb,              // [128]
    unsigned short* __restrict__ supT,         // [B][128f][1024m]
    unsigned short* __restrict__ resid)        // [B*N][128]
{
    const int t = threadIdx.x, w = t >> 6, l = t & 63;
    const int ln = l & 15, kb = l >> 4;
    const int mblk = w >> 1, fhalf = w & 1;
    const int row0 = blockIdx.x * 32;
    const int b   = row0 >> 10;
    const int mg0 = row0 & 1023;

    const float* xrow = x + (size_t)(row0 + mblk * 16 + ln) * 128;
    short8 xa[4];
#pragma unroll
    for (int k = 0; k < 4; ++k) {
        float4 v0 = *(const float4*)(xrow + k * 32 + kb * 8);
        float4 v1 = *(const float4*)(xrow + k * 32 + kb * 8 + 4);
        short8 s;
        s[0] = (short)f2bf(v0.x); s[1] = (short)f2bf(v0.y);
        s[2] = (short)f2bf(v0.z); s[3] = (short)f2bf(v0.w);
        s[4] = (short)f2bf(v1.x); s[5] = (short)f2bf(v1.y);
        s[6] = (short)f2bf(v1.z); s[7] = (short)f2bf(v1.w);
        xa[k] = s;
    }

    f32x4 accS[4], accR[4];
#pragma unroll
    for (int i = 0; i < 4; ++i) { accS[i] = (f32x4){0,0,0,0}; accR[i] = (f32x4){0,0,0,0}; }

#pragma unroll
    for (int k = 0; k < 4; ++k) {
#pragma unroll
        for (int fb = 0; fb < 4; ++fb) {
            int fr = (fhalf * 4 + fb) * 16 + ln;
            short8 wa = *(const short8*)(Wt  + (size_t)fr * 128 + k * 32 + kb * 8);
            short8 wb = *(const short8*)(rWt + (size_t)fr * 128 + k * 32 + kb * 8);
            accS[fb] = __builtin_amdgcn_mfma_f32_16x16x32_bf16(wa, xa[k], accS[fb], 0, 0, 0);
            accR[fb] = __builtin_amdgcn_mfma_f32_16x16x32_bf16(xa[k], wb, accR[fb], 0, 0, 0);
        }
    }

#pragma unroll
    for (int fb = 0; fb < 4; ++fb) {
        int m = mg0 + mblk * 16 + ln;
#pragma unroll
        for (int i = 0; i < 4; ++i) {
            int f = (fhalf * 4 + fb) * 16 + kb * 4 + i;
            supT[((size_t)b * 128 + f) * 1024 + m] = f2bf(accS[fb][i]);
        }
    }
#pragma unroll
    for (int fb = 0; fb < 4; ++fb) {
        int f = (fhalf * 4 + fb) * 16 + ln;
        float rbf = rb[f];
#pragma unroll
        for (int i = 0; i < 4; ++i) {
            size_t row = (size_t)row0 + mblk * 16 + kb * 4 + i;
            resid[row * 128 + f] = f2bf(fmaxf(accR[fb][i] + rbf, 0.f));
        }
    }
}

// ---------------------------------------------------------------------------
// K6: fused scores -> relu*adj -> conv -> epilogue.
// F-SPLIT for occupancy: block = (b, 32-row n-tile, 64-col f-half);
// grid 2048 (8 blocks/CU available), 256 thr / 4 waves, target 5 waves/SIMD.
// Scores duplicated across the f-pair (cheap: MFMA pipe ~7% busy).
// Score role: wave w -> n-tile sn=w>>1, m-pair sm=w&1 (block covers 32nx64m).
// Conv role:  wave w -> 16-row group cn=w&1, 32-col f group cf=w>>1.
// tgt/adj prefetched 2 chunks ahead, supT 1 chunk ahead (register dbuf);
// masked-A double-buffered in LDS; lgkm-only raw barrier per sub-iter.
// ---------------------------------------------------------------------------
__global__ __launch_bounds__(256, 5) void conv_mfma(
    const unsigned short* __restrict__ src_bf,  // [P][N][64]
    const unsigned short* __restrict__ tgt_bf,  // [P][N][64]
    const unsigned short* __restrict__ adj_bf,  // [N][N]
    const unsigned short* __restrict__ supT,    // [B][128][1024]
    const unsigned short* __restrict__ resid,   // [B*N][128]
    const float* __restrict__ bias,             // [128]
    const int* __restrict__ cyc,                // [B]
    float* __restrict__ out)                    // [B][N][128]
{
    __shared__ unsigned short s_a[2][32][72] __attribute__((aligned(16)));

    // chunked XCD swizzle: XCD k gets works [k*256,(k+1)*256) = 4 consecutive
    // b's; f-half pairs adjacent -> share tgt/adj/supT in the XCD's L2.
    const int i = blockIdx.x;                    // 0..2047
    const int work = (i & 7) * 256 + (i >> 3);
    const int fh   = work & 1;
    const int n0   = ((work >> 1) & 31) * 32;
    const int b    = work >> 6;

    const int t = threadIdx.x, w = t >> 6, l = t & 63;
    const int ln = l & 15, kb = l >> 4;
    const int p = ((cyc[b] % NPER) + NPER) % NPER;

    const int sn = w >> 1, sm = w & 1;   // score role
    const int cn = w & 1,  cf = w >> 1;  // conv role

    const unsigned short* srow = src_bf + ((size_t)p * N_ + n0 + sn * 16 + ln) * H_;
    const short8 sa0 = *(const short8*)(srow + kb * 8);
    const short8 sa1 = *(const short8*)(srow + 32 + kb * 8);

    const unsigned short* tbase = tgt_bf + (size_t)p * N_ * H_;
    const unsigned short* supb  = supT + ((size_t)b * 128 + fh * 64) * (size_t)N_;

    f32x4 acc[2];
    acc[0] = (f32x4){0, 0, 0, 0};
    acc[1] = (f32x4){0, 0, 0, 0};

    auto loadT = [&](int m0, short8 (&tb)[2][2], unsigned short (&av)[2][4]) {
#pragma unroll
        for (int mt = 0; mt < 2; ++mt) {
            const unsigned short* trow =
                tbase + (size_t)(m0 + (sm * 2 + mt) * 16 + ln) * H_;
            tb[mt][0] = *(const short8*)(trow + kb * 8);
            tb[mt][1] = *(const short8*)(trow + 32 + kb * 8);
            const int ml = (sm * 2 + mt) * 16 + ln;
#pragma unroll
            for (int ii = 0; ii < 4; ++ii)
                av[mt][ii] = adj_bf[(size_t)(n0 + sn * 16 + kb * 4 + ii) * N_ + m0 + ml];
        }
    };
    auto loadS = [&](int m0, short8 (&bs)[2][2]) {
#pragma unroll
        for (int ks = 0; ks < 2; ++ks)
#pragma unroll
            for (int fb = 0; fb < 2; ++fb)
                bs[ks][fb] = *(const short8*)(
                    supb + (size_t)(cf * 32 + fb * 16 + ln) * N_ + m0 + ks * 32 + kb * 8);
    };
    auto score = [&](const short8 (&tb)[2][2], const unsigned short (&av)[2][4], int wb) {
#pragma unroll
        for (int mt = 0; mt < 2; ++mt) {
            f32x4 c = (f32x4){0, 0, 0, 0};
            c = __builtin_amdgcn_mfma_f32_16x16x32_bf16(sa0, tb[mt][0], c, 0, 0, 0);
            c = __builtin_amdgcn_mfma_f32_16x16x32_bf16(sa1, tb[mt][1], c, 0, 0, 0);
            const int ml = (sm * 2 + mt) * 16 + ln;
#pragma unroll
            for (int ii = 0; ii < 4; ++ii) {
                float a2 = fmaxf(c[ii], 0.f) * bf2f(av[mt][ii]);
                s_a[wb][sn * 16 + kb * 4 + ii][ml] = f2bf_hw(a2);
            }
        }
    };
    auto conv = [&](int rb, const short8 (&bs)[2][2]) {
#pragma unroll
        for (int ks = 0; ks < 2; ++ks) {
            short8 af = *(const short8*)(&s_a[rb][cn * 16 + ln][ks * 32 + kb * 8]);
#pragma unroll
            for (int fb = 0; fb < 2; ++fb)
                acc[fb] = __builtin_amdgcn_mfma_f32_16x16x32_bf16(af, bs[ks][fb], acc[fb], 0, 0, 0);
        }
    };

    // LDS-visibility barrier only: per-wave lgkm drain + raw barrier;
    // global prefetches stay in flight across it.
    auto barrier_lds = []() {
        asm volatile("s_waitcnt lgkmcnt(0)" ::: "memory");
        __builtin_amdgcn_s_barrier();
    };

    short8 tbA[2][2], tbB[2][2];
    unsigned short adjA[2][4], adjB[2][4];
    short8 bsA[2][2], bsB[2][2];

    // prologue
    loadT(0, tbA, adjA);
    loadT(64, tbB, adjB);
    loadS(0, bsA);
    score(tbA, adjA, 0);
    barrier_lds();

    for (int tt = 0; tt < 16; tt += 2) {
        // sub-iter tt: conv chunk tt (bsA, buf0); score chunk tt+1 (tbB -> buf1)
        loadS((tt + 1) * 64, bsB);
        if (tt + 2 < 16) loadT((tt + 2) * 64, tbA, adjA);
        __builtin_amdgcn_sched_barrier(0);   // pin load issue before compute
        conv(0, bsA);
        score(tbB, adjB, 1);
        barrier_lds();

        // sub-iter tt+1: conv chunk tt+1 (bsB, buf1); score chunk tt+2 (tbA -> buf0)
        if (tt + 2 < 16) loadS((tt + 2) * 64, bsA);
        if (tt + 3 < 16) loadT((tt + 3) * 64, tbB, adjB);
        __builtin_amdgcn_sched_barrier(0);
        conv(1, bsB);
        if (tt + 2 < 16) {
            score(tbA, adjA, 0);
            barrier_lds();
        }
    }

    // epilogue: out = relu(conv + bias + residual)
#pragma unroll
    for (int fb = 0; fb < 2; ++fb) {
        const int f = fh * 64 + cf * 32 + fb * 16 + ln;
        const float bi = bias[f];
#pragma unroll
        for (int ii = 0; ii < 4; ++ii) {
            const int n = n0 + cn * 16 + kb * 4 + ii;
            const size_t o = ((size_t)b * N_ + n) * F_ + f;
            out[o] = fmaxf(acc[fb][ii] + bi + bf2f(resid[o]), 0.f);
        }
    }
}

// ---------------------------------------------------------------------------
extern "C" void kernel_launch(void* const* d_in, const int* in_sizes, int n_in,
                              void* d_out, int out_size, void* d_ws, size_t ws_size,
                              hipStream_t stream) {
    const float* input_features = (const float*)d_in[0];
    const int*   cycle_indices  = (const int*)  d_in[1];
    const float* weight         = (const float*)d_in[2];
    const float* bias           = (const float*)d_in[3];
    const float* src_emb        = (const float*)d_in[4];
    const float* tgt_emb        = (const float*)d_in[5];
    const float* env_W          = (const float*)d_in[6];
    const float* env_b          = (const float*)d_in[7];
    const float* res_W          = (const float*)d_in[8];
    const float* res_b          = (const float*)d_in[9];
    const float* static_adj     = (const float*)d_in[10];
    const float* env_features   = (const float*)d_in[11];
    float* out = (float*)d_out;

    // workspace layout (~25.2 MiB)
    char* wsb = (char*)d_ws;
    unsigned short* src_bf = (unsigned short*)wsb;               // 3145728 B
    unsigned short* tgt_bf = src_bf + (size_t)NPER * N_ * H_;    // 3145728 B
    unsigned short* Wt     = tgt_bf + (size_t)NPER * N_ * H_;    // 32768 B
    unsigned short* rWt    = Wt + 16384;                         // 32768 B
    unsigned short* supT   = rWt + 16384;                        // 8388608 B
    unsigned short* resid  = supT + (size_t)B_ * F_ * N_;        // 8388608 B
    unsigned short* adj_bf = resid + (size_t)B_ * N_ * F_;       // 2097152 B

    prep_all<<<1408, 256, 0, stream>>>(
        src_emb, tgt_emb, env_features, env_W, env_b,
        static_adj, weight, res_W,
        src_bf, tgt_bf, adj_bf, Wt, rWt);

    gemm2_mfma<<<(B_ * N_) / 32, 256, 0, stream>>>(
        input_features, Wt, rWt, res_b, supT, resid);

    conv_mfma<<<2048, 256, 0, stream>>>(
        src_bf, tgt_bf, adj_bf, supT, resid, bias, cycle_indices, out);
}